// Round 3
// baseline (579.604 us; speedup 1.0000x reference)
//
#include <hip/hip_runtime.h>
#include <math.h>

#define NATOM 2048
#define CD 128
#define SD 2
#define TT 512
#define CTD 384
#define NBI 3
#define MR 4096  // SD*NATOM

typedef unsigned short ushortx;
typedef __attribute__((ext_vector_type(8))) short bf16x8;
typedef __attribute__((ext_vector_type(4))) float f32x4;
typedef __attribute__((ext_vector_type(4))) unsigned short us4;

__device__ __forceinline__ float sigm(float x){ return 1.0f/(1.0f+expf(-x)); }
__device__ __forceinline__ ushortx f2b(float f){
  union { float f; unsigned u; } v; v.f = f;
  unsigned r = v.u + 0x7fffu + ((v.u>>16)&1u);
  return (ushortx)(r>>16);
}
__device__ __forceinline__ float b2f(ushortx u){
  union { unsigned u; float f; } v; v.u = ((unsigned)u)<<16; return v.f;
}
union U8 { ushortx u[8]; float4 v; };

// ---- workspace layout (byte offsets, 256-aligned) ----
#define OFFB_W3T    0ll        // ushort 6*384*128   [n][k] [gate|shift|og]
#define OFFB_B3     589824ll   // f32 6*384
#define OFFB_WQKVGT 599040ll   // ushort 3*512*128
#define OFFB_BQ     992256ll   // f32 3*512
#define OFFB_WOUTT  998400ll   // ushort 3*128*128
#define OFFB_WABT   1096704ll  // ushort 3*512*128
#define OFFB_WTOUTT 1489920ll  // ushort 3*128*256
#define OFFB_WTOKT  1686528ll  // ushort 384*128
#define OFFB_SNP    2833408ll  // ushort 6*2048*384 (bf16)
#define OFFB_A      12270592ll // f32 4096*128
#define OFFB_QKVG   14367744ll // ushort 4096*512 (bf16)
#define OFFB_ZB     18562048ll // ushort 3*8*2048*128 (bf16)
#define OFFB_QTOK   31144960ll // f32 4096*384
#define OFFB_QKVG2  37436416ll // ushort 4096*512 (bf16, ping-pong partner)

struct WPtrs {
  const float *aln_gate_w, *aln_gate_b, *aln_shift_w, *og_w, *og_b;
  const float *t_aln_gate_w, *t_aln_gate_b, *t_aln_shift_w, *t_og_w, *t_og_b;
  const float *q_w, *q_b, *k_w, *v_w, *gate_w, *out_w;
  const float *t_a_w, *t_b_w, *t_out_w, *tok_w;
};

// merged prologue: weight pack (blocks 0..3470) + zb compute (3471..4494).
__global__ __launch_bounds__(256) void prologue_kernel(WPtrs P, char* __restrict__ wsb,
  const float* __restrict__ atom_pair,
  const float* __restrict__ plw, const float* __restrict__ plb, const float* __restrict__ pw)
{
  int b = blockIdx.x;
  if (b < 3471){
    long long idx = (long long)b*256 + threadIdx.x;
    const long long s0=294912, s1=2304, s2=196608, s3=1536, s4=49152, s5=196608, s6=98304;
    if (idx < s0) { // W3T[which][n][k]
      int which = (int)(idx/49152); int r = (int)(idx%49152); int n=r/128, k=r%128;
      int i = which>>1, t = which&1;
      const float* src;
      if (n<128)      src = (t?P.t_aln_gate_w :P.aln_gate_w ) + i*16384 + k*128 + n;
      else if (n<256) src = (t?P.t_aln_shift_w:P.aln_shift_w) + i*16384 + k*128 + (n-128);
      else            src = (t?P.t_og_w       :P.og_w       ) + i*16384 + k*128 + (n-256);
      ((ushortx*)(wsb+OFFB_W3T))[idx] = f2b(*src); return;
    }
    idx -= s0;
    if (idx < s1) {
      int which = (int)(idx/384); int col = (int)(idx%384); int i=which>>1, t=which&1;
      float v = 0.f;
      if (col<128)       v = (t?P.t_aln_gate_b:P.aln_gate_b)[i*128+col];
      else if (col>=256) v = (t?P.t_og_b      :P.og_b      )[i*128+col-256];
      ((float*)(wsb+OFFB_B3))[idx] = v; return;
    }
    idx -= s1;
    if (idx < s2) { // WQKVGT[i][n][k]
      int i = (int)(idx/65536); int r = (int)(idx%65536); int n=r/128, k=r%128;
      int seg = n>>7, c = n&127;
      const float* src = (seg==0?P.q_w: seg==1?P.k_w: seg==2?P.v_w: P.gate_w) + i*16384 + k*128 + c;
      ((ushortx*)(wsb+OFFB_WQKVGT))[idx] = f2b(*src); return;
    }
    idx -= s2;
    if (idx < s3) {
      int i = (int)(idx/512); int col = (int)(idx%512);
      ((float*)(wsb+OFFB_BQ))[idx] = (col<128) ? P.q_b[i*128+col] : 0.f; return;
    }
    idx -= s3;
    if (idx < s4) { // WOUTT
      int i = (int)(idx/16384); int r = (int)(idx%16384); int n=r/128, k=r%128;
      ((ushortx*)(wsb+OFFB_WOUTT))[idx] = f2b(P.out_w[i*16384 + k*128 + n]); return;
    }
    idx -= s4;
    if (idx < s5) { // WABT
      int i = (int)(idx/65536); int r = (int)(idx%65536); int n=r/128, k=r%128;
      const float* src = (n<256) ? P.t_a_w + i*32768 + k*256 + n
                                 : P.t_b_w + i*32768 + k*256 + (n-256);
      ((ushortx*)(wsb+OFFB_WABT))[idx] = f2b(*src); return;
    }
    idx -= s5;
    if (idx < s6) { // WTOUTT
      int i = (int)(idx/32768); int r = (int)(idx%32768); int n=r/256, k=r%256;
      ((ushortx*)(wsb+OFFB_WTOUTT))[idx] = f2b(P.t_out_w[i*32768 + k*128 + n]); return;
    }
    idx -= s6;
    { // WTOKT
      int n = (int)(idx/128); int k = (int)(idx%128);
      ((ushortx*)(wsb+OFFB_WTOKT))[idx] = f2b(P.tok_w[k*384 + n]); return;
    }
  }
  // zb part: zb_all[it][h][q][j] bf16, j in [0,128): key m = (q&~31)-48+j
  {
    int idx = (b-3471)*256 + threadIdx.x;
    int q = idx>>7, j = idx&127;
    int m = (q & ~31) - 48 + j;
    bool ok = (m>=0 && m<NATOM);
    float x[16]; float mu=0.f, rs=0.f;
    if (ok){
      float s=0.f, sq=0.f;
      const float* p = atom_pair + ((long long)q*NATOM + m)*16;
      #pragma unroll
      for (int c=0;c<16;c++){ x[c]=p[c]; s+=x[c]; sq+=x[c]*x[c]; }
      mu = s*(1.f/16.f); float var = sq*(1.f/16.f)-mu*mu; rs = rsqrtf(var+1e-5f);
    }
    ushortx* zb = (ushortx*)(wsb+OFFB_ZB);
    #pragma unroll
    for (int it=0; it<NBI; it++){
      float out[8] = {0,0,0,0,0,0,0,0};
      if (ok){
        #pragma unroll
        for (int c=0;c<16;c++){
          float xn = (x[c]-mu)*rs*plw[it*16+c] + plb[it*16+c];
          #pragma unroll
          for (int h=0;h<8;h++) out[h] += xn * pw[it*128 + c*8 + h];
        }
      }
      #pragma unroll
      for (int h=0;h<8;h++)
        zb[(((long long)it*8+h)*NATOM + q)*128 + j] = f2b(out[h]);
    }
  }
}

// Fused iteration: banded attention (per-head, double-buffered LDS) + full
// post-attention chain, row-local (16 rows/block, 256 blocks).
//   attn: A1[16][128] into LDS (never global)
//   p 0..1 : Af += sigm(ogA)*(A1 @ Wout)
//   p 2..9 : a2=modln_T(Af); h = a2 @ Wab   (hidden stays in LDS)
//   p10..13: Af += sigm(ogT)*(silu(h_a)*h_b @ Wtout)   (K=256)
//   p14..  : write Af; LAST? qtok=relu(Af@Wtok) : qkvg_next=modln_N(Af)@WN+bq
template<int LAST>
__global__ __launch_bounds__(256) void fused_iter(
  const float* __restrict__ Afsrc,     // atom_single (iter0) or Af
  float* __restrict__ Af,
  const ushortx* __restrict__ QKVGin,  // this iter's qkvg (bf16)
  const ushortx* __restrict__ zb,      // this iter's zb [8][2048][128]
  const float* __restrict__ mask,
  const ushortx* __restrict__ Wout,    // [128][128]
  const ushortx* __restrict__ Wab,     // [512][128]
  const ushortx* __restrict__ Wtout,   // [128][256]
  const ushortx* __restrict__ WN,      // qkvg_next [512][128] | tok [384][128]
  const float*   __restrict__ biasN,   // [512] (null if LAST)
  const ushortx* __restrict__ snpA,    // this iter A-side [2048][384]
  const ushortx* __restrict__ snpT,    // this iter T-side
  const ushortx* __restrict__ snpN,    // next iter A-side (null if LAST)
  ushortx* __restrict__ QKVGout,       // out (non-last; ping-pong partner)
  float*   __restrict__ QTOK)          // out (last)
{
  __shared__ __align__(16) ushortx Bt[2][64][136];
  __shared__ __align__(16) float   Afr[16][132];
  __shared__ __align__(16) ushortx A2t[16][136];
  __shared__ __align__(16) ushortx Ht[16][264];   // raw h_a (bf16)
  __shared__ __align__(16) ushortx XX[16*264];    // A1t (p<2) then Hs (p>=6)
  __shared__ __align__(16) ushortx Kh[2][128][24];
  __shared__ __align__(16) ushortx Vh[2][128][24];
  __shared__ __align__(16) ushortx Zh[2][16][136];
  __shared__ __align__(16) ushortx Qh[2][16][16];
  __shared__ __align__(16) ushortx Gh[2][16][16];
  __shared__ __align__(16) float   Ls[16][132];
  __shared__ __align__(16) ushortx SnpT[16][392]; // full rows: gate|shift|og
  __shared__ __align__(16) ushortx SnpN[16][392];
  __shared__ __align__(16) ushortx SnpAog[16][136];
  __shared__ float maskb[128];
  ushortx (*A1t)[136] = (ushortx(*)[136])XX;
  ushortx (*Hs)[264]  = (ushortx(*)[264])XX;

  int tid = threadIdx.x, rowBase = blockIdx.x*16;
  int sIdx = rowBase >> 11;            // which s
  int n0 = rowBase & 2047;             // atom index base
  int wbase = (n0 & ~31) - 48;         // key-window base (shared by all 16 rows)
  int wave=tid>>6, lane=tid&63, lr=lane&15, lk=(lane>>4)*8;
  int wc = wave*16;
  int r = tid>>4, tcol = tid&15, c8 = tcol*8;
  long long grow = rowBase + r;
  int sr=tid>>2, csB=(tid&3)*32;
  int crow = (lane>>4)*4;

  // ---- initial staging ----
  { const float4* ap=(const float4*)&Afsrc[grow*128+c8];
    *(float4*)&Afr[r][c8]=ap[0]; *(float4*)&Afr[r][c8+4]=ap[1]; }
  if (tid < 128){
    int m = wbase + tid;
    maskb[tid] = (m>=0 && m<NATOM) ? (mask[m]-1.0f)*1e8f : -1e30f;
  }
  #pragma unroll
  for (int k=0;k<3;k++){ int idx=tid+k*256; int rr=idx/48, cc=(idx%48)*8;
    *(float4*)&SnpT[rr][cc] = *(const float4*)&snpT[(long long)((rowBase+rr)&2047)*384 + cc]; }
  if (!LAST){
    #pragma unroll
    for (int k=0;k<3;k++){ int idx=tid+k*256; int rr=idx/48, cc=(idx%48)*8;
      *(float4*)&SnpN[rr][cc] = *(const float4*)&snpN[(long long)((rowBase+rr)&2047)*384 + cc]; }
  }
  *(float4*)&SnpAog[r][c8] = *(const float4*)&snpA[(long long)((rowBase+r)&2047)*384 + 256 + c8];
  { // Bt[0] for pass 0 (Wout cols 0..63)
    const float4* bg = (const float4*)(Wout + (long long)sr*128 + csB);
    #pragma unroll
    for (int u=0;u<4;u++) *(float4*)&Bt[0][sr][csB+u*8] = bg[u];
  }

  // ---- attention phase ----
  int jr=tid>>1, hf=tid&1;
  int mm=wbase+jr; int mc = mm<0?0:(mm>NATOM-1?NATOM-1:mm);
  long long krow = ((long long)(sIdx*NATOM+mc))*512;
  auto issue = [&](int h, float4&kreg, float4&vreg, float4&zreg, float4&qg){
    kreg = *(const float4*)&QKVGin[krow + 128 + h*16 + hf*8];
    vreg = *(const float4*)&QKVGin[krow + 256 + h*16 + hf*8];
    zreg = *(const float4*)&zb[((long long)h*NATOM + n0 + r)*128 + c8];
    if (tid < 32)
      qg = *(const float4*)&QKVGin[((long long)(rowBase+(tid>>1)))*512 + h*16 + (tid&1)*8];
    else if (tid < 64){
      int tt=tid-32;
      qg = *(const float4*)&QKVGin[((long long)(rowBase+(tt>>1)))*512 + 384 + h*16 + (tt&1)*8];
    }
  };
  auto commit = [&](int bb, float4 kreg, float4 vreg, float4 zreg, float4 qg){
    *(float4*)&Kh[bb][jr][hf*8] = kreg;
    *(float4*)&Vh[bb][jr][hf*8] = vreg;
    *(float4*)&Zh[bb][r][c8] = zreg;
    if (tid < 32) *(float4*)&Qh[bb][tid>>1][(tid&1)*8] = qg;
    else if (tid < 64){ int tt=tid-32; *(float4*)&Gh[bb][tt>>1][(tt&1)*8] = qg; }
  };
  { float4 k0,v0,z0,q0 = make_float4(0,0,0,0);
    issue(0,k0,v0,z0,q0); commit(0,k0,v0,z0,q0); }
  __syncthreads();
  for (int h=0; h<8; ++h){
    int bb=h&1;
    float4 kn,vn,zn,qn = make_float4(0,0,0,0);
    if (h<7) issue(h+1,kn,vn,zn,qn);   // loads in flight under compute
    float qv[16];
    { U8 qa,qb_;
      qa.v=*(const float4*)&Qh[bb][r][0]; qb_.v=*(const float4*)&Qh[bb][r][8];
      #pragma unroll
      for (int t=0;t<8;t++){ qv[t]=b2f(qa.u[t]); qv[8+t]=b2f(qb_.u[t]); } }
    float lv[8], pmax=-1e30f;
    #pragma unroll
    for (int u=0;u<8;u++){
      int j=tcol+u*16;
      U8 ka,kb_;
      ka.v=*(const float4*)&Kh[bb][j][0]; kb_.v=*(const float4*)&Kh[bb][j][8];
      float dot=0.f;
      #pragma unroll
      for (int t=0;t<8;t++) dot += qv[t]*b2f(ka.u[t]);
      #pragma unroll
      for (int t=0;t<8;t++) dot += qv[8+t]*b2f(kb_.u[t]);
      float L = dot*0.25f + b2f(Zh[bb][r][j]) + maskb[j];
      lv[u]=L; pmax=fmaxf(pmax,L);
    }
    #pragma unroll
    for (int off=1; off<16; off<<=1) pmax = fmaxf(pmax, __shfl_xor(pmax,off));
    float ps=0.f;
    #pragma unroll
    for (int u=0;u<8;u++){ float e=expf(lv[u]-pmax); Ls[r][tcol+u*16]=e; ps+=e; }
    #pragma unroll
    for (int off=1; off<16; off<<=1) ps += __shfl_xor(ps,off);
    float inv = 1.0f/ps;
    __syncthreads();                    // Ls fully written before cross-lane PV
    float a0=0.f;
    #pragma unroll 4
    for (int j=0;j<128;j++) a0 += Ls[r][j]*b2f(Vh[bb][j][tcol]);
    float gt = b2f(Gh[bb][r][tcol]);
    A1t[r][h*16+tcol] = f2b(sigm(gt)*a0*inv);
    if (h<7) commit((h+1)&1,kn,vn,zn,qn);
    __syncthreads();                    // buf h+1 ready; Ls safe to overwrite
  }

  // ---- GEMM pass loop ----
  const int NP = LAST ? 20 : 22;
  f32x4 acc = (f32x4){0.f,0.f,0.f,0.f};
  for (int p=0; p<NP; p++){
    __syncthreads();
    if (p+1 < NP){
      int pn = p+1;
      const ushortx* bsrc; long long bstride;
      if (pn<2)      { bsrc = Wout  + (long long)(pn*64)*128;                      bstride=128; }
      else if (pn<10){ bsrc = Wab   + (long long)((pn-2)*64)*128;                  bstride=128; }
      else if (pn<14){ int q=pn-10; bsrc = Wtout + (long long)((q>>1)*64)*256 + (q&1)*128; bstride=256; }
      else           { int q=pn-14; bsrc = WN    + (long long)(q*64)*128;          bstride=128; }
      const float4* bg=(const float4*)(bsrc + (long long)sr*bstride + csB);
      #pragma unroll
      for (int u=0;u<4;u++) *(float4*)&Bt[pn&1][sr][csB+u*8] = bg[u];
    }
    if (p==2){
      float x[8], s=0.f, sq=0.f;
      #pragma unroll
      for (int u=0;u<8;u++){ x[u]=Afr[r][c8+u]; s+=x[u]; sq+=x[u]*x[u]; }
      #pragma unroll
      for (int off=1; off<16; off<<=1){ s+=__shfl_xor(s,off); sq+=__shfl_xor(sq,off); }
      float mu=s*(1.f/128.f), rs=rsqrtf(sq*(1.f/128.f)-mu*mu+1e-5f);
      U8 ga,ha,pk;
      ga.v=*(const float4*)&SnpT[r][c8]; ha.v=*(const float4*)&SnpT[r][128+c8];
      #pragma unroll
      for (int t=0;t<8;t++) pk.u[t]=f2b(sigm(b2f(ga.u[t]))*((x[t]-mu)*rs)+b2f(ha.u[t]));
      *(float4*)&A2t[r][c8]=pk.v;
      __syncthreads();
    }
    if (p==14){
      float x[8], s=0.f, sq=0.f;
      #pragma unroll
      for (int u=0;u<8;u++){ x[u]=Afr[r][c8+u]; s+=x[u]; sq+=x[u]*x[u]; }
      { float4* ap=(float4*)&Af[grow*128+c8];
        ap[0]=*(float4*)&Afr[r][c8]; ap[1]=*(float4*)&Afr[r][c8+4]; }
      if (LAST){
        U8 pk;
        #pragma unroll
        for (int t=0;t<8;t++) pk.u[t]=f2b(x[t]);
        *(float4*)&A2t[r][c8]=pk.v;
      } else {
        #pragma unroll
        for (int off=1; off<16; off<<=1){ s+=__shfl_xor(s,off); sq+=__shfl_xor(sq,off); }
        float mu=s*(1.f/128.f), rs=rsqrtf(sq*(1.f/128.f)-mu*mu+1e-5f);
        U8 ga,ha,pk;
        ga.v=*(const float4*)&SnpN[r][c8]; ha.v=*(const float4*)&SnpN[r][128+c8];
        #pragma unroll
        for (int t=0;t<8;t++) pk.u[t]=f2b(sigm(b2f(ga.u[t]))*((x[t]-mu)*rs)+b2f(ha.u[t]));
        *(float4*)&A2t[r][c8]=pk.v;
      }
      __syncthreads();
    }
    if (p!=11 && p!=13) acc=(f32x4){0.f,0.f,0.f,0.f};
    #pragma unroll
    for (int ks=0; ks<4; ks++){
      bf16x8 a;
      if (p<2)       a = *(const bf16x8*)&A1t[lr][ks*32+lk];
      else if (p<10) a = *(const bf16x8*)&A2t[lr][ks*32+lk];
      else if (p<14){ int kc=(p-10)&1; a = *(const bf16x8*)&Hs[lr][kc*128+ks*32+lk]; }
      else           a = *(const bf16x8*)&A2t[lr][ks*32+lk];
      bf16x8 b = *(const bf16x8*)&Bt[p&1][wc+lr][ks*32+lk];
      acc = __builtin_amdgcn_mfma_f32_16x16x32_bf16(a,b,acc,0,0,0);
    }
    if (p<2){
      int ccol = p*64 + wc + lr;
      #pragma unroll
      for (int rr=0;rr<4;rr++){
        int rrow=crow+rr;
        float g=b2f(SnpAog[rrow][ccol]);
        Afr[rrow][ccol]+=sigm(g)*acc[rr];
      }
    } else if (p<10){
      int cp=p-2; int ccol=cp*64+wc+lr;
      if (cp<4){
        #pragma unroll
        for (int rr=0;rr<4;rr++) Ht[crow+rr][ccol]=f2b(acc[rr]);
      } else {
        int hc=ccol-256;
        #pragma unroll
        for (int rr=0;rr<4;rr++){
          float ha=b2f(Ht[crow+rr][hc]);
          Hs[crow+rr][hc]=f2b(ha*sigm(ha)*acc[rr]);
        }
      }
    } else if (p==11 || p==13){
      int cp=(p-10)>>1; int ccol=cp*64+wc+lr;
      #pragma unroll
      for (int rr=0;rr<4;rr++){
        int rrow=crow+rr;
        float g=b2f(SnpT[rrow][256+ccol]);
        Afr[rrow][ccol]+=sigm(g)*acc[rr];
      }
    } else if (p>=14){
      int q=p-14; int ccol=q*64+wc+lr;
      if (LAST){
        #pragma unroll
        for (int rr=0;rr<4;rr++)
          QTOK[(long long)(rowBase+crow+rr)*384 + ccol]=fmaxf(acc[rr],0.f);
      } else {
        float bv=biasN[ccol];
        #pragma unroll
        for (int rr=0;rr<4;rr++)
          QKVGout[(long long)(rowBase+crow+rr)*512 + ccol]=f2b(acc[rr]+bv);
      }
    }
  }
}

// MFMA GEMM with fused A-staging (SNP production and qkvg0).
template<int AM, int BM>
__global__ __launch_bounds__(256) void gemm_f(
    const void* __restrict__ Asrc, long long strideA,
    const ushortx* __restrict__ B, long long strideB,
    const float* __restrict__ bias, long long strideBias,
    void* Cv, long long strideC,
    int M, int N, int K, int mode,
    const void* __restrict__ p1, const void* __restrict__ p2,
    const void* __restrict__ p3, const void* __restrict__ p4)
{
  constexpr int CG  = 256/BM;
  constexpr int XC  = 128/CG;
  constexpr int F4  = XC/8;
  constexpr int ACI = BM/32;
  int z = blockIdx.z;
  B += z*strideB;
  if (bias) bias += z*strideBias;
  float* C = (float*)Cv + z*strideC;
  ushortx* Cu = (ushortx*)Cv + z*strideC;
  __shared__ __align__(16) ushortx At[BM][136];
  __shared__ __align__(16) ushortx Bt[64][136];
  int tid = threadIdx.x;
  int rowBase = blockIdx.y*BM, colBase = blockIdx.x*64;
  int wave = tid>>6, lane = tid&63;
  int wr = (wave>>1)*(BM/2), wc = (wave&1)*32;
  int lr = lane&15, lk = (lane>>4)*8;
  f32x4 acc[ACI][2];
  #pragma unroll
  for (int i=0;i<ACI;i++)
    #pragma unroll
    for (int j=0;j<2;j++) acc[i][j] = (f32x4){0.f,0.f,0.f,0.f};

  int sr = tid/CG, q = tid%CG, cs = q*XC;
  int row = rowBase + sr;
  int bsr = tid>>2, bq = tid&3, bcs = bq*32;

  for (int kc=0; kc<K; kc+=128){
    if (kc) __syncthreads();
    { // AM==1 or AM==4: LN staging, K=128
      const float* arow = (const float*)Asrc + (long long)row*128;
      float x[XC]; float s=0.f, sq=0.f;
      const float4* ar = (const float4*)(arow + cs);
      #pragma unroll
      for (int u=0;u<XC/4;u++){
        float4 t = ar[u];
        x[4*u]=t.x; x[4*u+1]=t.y; x[4*u+2]=t.z; x[4*u+3]=t.w;
        s += t.x+t.y+t.z+t.w;
        sq += t.x*t.x+t.y*t.y+t.z*t.z+t.w*t.w;
      }
      #pragma unroll
      for (int off=1; off<CG; off<<=1){ s += __shfl_xor(s,off); sq += __shfl_xor(sq,off); }
      float mu = s*(1.f/128.f), var = sq*(1.f/128.f)-mu*mu;
      float rs = rsqrtf(var + 1e-5f);
      if (AM==1){
        const ushortx* sp = (const ushortx*)p1 + (long long)(row & (NATOM-1))*384;
        const float4* gr = (const float4*)(sp + cs);
        const float4* hr = (const float4*)(sp + 128 + cs);
        #pragma unroll
        for (int u=0;u<F4;u++){
          U8 ga, ha, pk;
          ga.v = gr[u]; ha.v = hr[u];
          #pragma unroll
          for (int t=0;t<8;t++)
            pk.u[t] = f2b(sigm(b2f(ga.u[t]))*((x[8*u+t]-mu)*rs) + b2f(ha.u[t]));
          *(float4*)&At[sr][cs+u*8] = pk.v;
        }
      } else { // AM==4
        int iw = z>>1, tw = z&1;
        const float* w = (const float*)(tw?p3:p1) + iw*128;
        const float* b = (const float*)(tw?p4:p2) + iw*128;
        const float4* wrp = (const float4*)(w + cs);
        const float4* brp = (const float4*)(b + cs);
        #pragma unroll
        for (int u=0;u<F4;u++){
          float4 wa = wrp[2*u], wb = wrp[2*u+1];
          float4 ba = brp[2*u], bb = brp[2*u+1];
          U8 pk;
          pk.u[0]=f2b((x[8*u  ]-mu)*rs*wa.x+ba.x);
          pk.u[1]=f2b((x[8*u+1]-mu)*rs*wa.y+ba.y);
          pk.u[2]=f2b((x[8*u+2]-mu)*rs*wa.z+ba.z);
          pk.u[3]=f2b((x[8*u+3]-mu)*rs*wa.w+ba.w);
          pk.u[4]=f2b((x[8*u+4]-mu)*rs*wb.x+bb.x);
          pk.u[5]=f2b((x[8*u+5]-mu)*rs*wb.y+bb.y);
          pk.u[6]=f2b((x[8*u+6]-mu)*rs*wb.z+bb.z);
          pk.u[7]=f2b((x[8*u+7]-mu)*rs*wb.w+bb.w);
          *(float4*)&At[sr][cs+u*8] = pk.v;
        }
      }
    }
    {
      const float4* bg = (const float4*)(B + (long long)(colBase+bsr)*K + kc + bcs);
      #pragma unroll
      for (int u=0;u<4;u++) *(float4*)&Bt[bsr][bcs+u*8] = bg[u];
    }
    __syncthreads();
    #pragma unroll
    for (int ks=0; ks<4; ks++){
      bf16x8 b0 = *(const bf16x8*)&Bt[wc+lr][ks*32+lk];
      bf16x8 b1 = *(const bf16x8*)&Bt[wc+16+lr][ks*32+lk];
      #pragma unroll
      for (int i=0;i<ACI;i++){
        bf16x8 a = *(const bf16x8*)&At[wr+i*16+lr][ks*32+lk];
        acc[i][0] = __builtin_amdgcn_mfma_f32_16x16x32_bf16(a,b0,acc[i][0],0,0,0);
        acc[i][1] = __builtin_amdgcn_mfma_f32_16x16x32_bf16(a,b1,acc[i][1],0,0,0);
      }
    }
  }
  int crow0 = rowBase + wr + (lane>>4)*4;
  int ccol0 = colBase + wc + lr;
  #pragma unroll
  for (int i=0;i<ACI;i++){
    #pragma unroll
    for (int j=0;j<2;j++){
      int col = ccol0 + j*16;
      float bv = bias ? bias[col] : 0.f;
      #pragma unroll
      for (int rr=0; rr<4; rr++){
        int rrow = crow0 + i*16 + rr;
        float v = acc[i][j][rr] + bv;
        long long ci = (long long)rrow*N + col;
        Cu[ci] = f2b(v);   // mode 3 (store bf16) is the only used mode
        (void)C; (void)mode;
      }
    }
  }
}

__global__ __launch_bounds__(128) void tokagg_kernel(const int* __restrict__ tok_idx,
    const float* __restrict__ qtok, float* __restrict__ out)
{
  int t = blockIdx.x;
  int lo=0, hi=NATOM;
  while (lo<hi){ int mid=(lo+hi)>>1; if (tok_idx[mid] < t) lo=mid+1; else hi=mid; }
  int start = lo;
  lo = start; hi = NATOM;
  while (lo<hi){ int mid=(lo+hi)>>1; if (tok_idx[mid] <= t) lo=mid+1; else hi=mid; }
  int end = lo;
  int cnt = end - start;
  float inv = 1.0f / (float)(cnt>0 ? cnt : 1);
  for (int s=0; s<SD; s++)
    for (int c=threadIdx.x; c<CTD; c+=128){
      float acc = 0.f;
      for (int n=start; n<end; n++) acc += qtok[((long long)(s*NATOM+n))*CTD + c];
      out[(long long)(s*TT + t)*CTD + c] = acc*inv;
    }
}

extern "C" void kernel_launch(void* const* d_in, const int* in_sizes, int n_in,
                              void* d_out, int out_size, void* d_ws, size_t ws_size,
                              hipStream_t stream)
{
  const float* atom_single = (const float*)d_in[0];
  const float* atom_proj   = (const float*)d_in[1];
  const float* atom_pair   = (const float*)d_in[2];
  const float* mask        = (const float*)d_in[3];
  const int*   tok_idx     = (const int*)  d_in[4];
  const float* aln_s_w     = (const float*)d_in[5];
  const float* aln_s_b     = (const float*)d_in[6];
  const float* pair_ln_w   = (const float*)d_in[14];
  const float* pair_ln_b   = (const float*)d_in[15];
  const float* pair_w      = (const float*)d_in[16];
  const float* t_aln_s_w   = (const float*)d_in[21];
  const float* t_aln_s_b   = (const float*)d_in[22];

  char* wsb = (char*)d_ws;
  ushortx* W3T    = (ushortx*)(wsb+OFFB_W3T);
  float*   B3     = (float*)  (wsb+OFFB_B3);
  ushortx* WQKVGT = (ushortx*)(wsb+OFFB_WQKVGT);
  float*   BQ     = (float*)  (wsb+OFFB_BQ);
  ushortx* WOUTT  = (ushortx*)(wsb+OFFB_WOUTT);
  ushortx* WABT   = (ushortx*)(wsb+OFFB_WABT);
  ushortx* WTOUTT = (ushortx*)(wsb+OFFB_WTOUTT);
  ushortx* WTOKT  = (ushortx*)(wsb+OFFB_WTOKT);
  ushortx* SNP    = (ushortx*)(wsb+OFFB_SNP);
  float*   Af     = (float*)  (wsb+OFFB_A);
  ushortx* QKVG   = (ushortx*)(wsb+OFFB_QKVG);
  ushortx* QKVG2  = (ushortx*)(wsb+OFFB_QKVG2);
  ushortx* ZB     = (ushortx*)(wsb+OFFB_ZB);
  float*   QTOK   = (float*)  (wsb+OFFB_QTOK);

  WPtrs P;
  P.aln_gate_w=(const float*)d_in[7];  P.aln_gate_b=(const float*)d_in[8];  P.aln_shift_w=(const float*)d_in[9];
  P.og_w=(const float*)d_in[19]; P.og_b=(const float*)d_in[20];
  P.t_aln_gate_w=(const float*)d_in[23]; P.t_aln_gate_b=(const float*)d_in[24]; P.t_aln_shift_w=(const float*)d_in[25];
  P.t_og_w=(const float*)d_in[29]; P.t_og_b=(const float*)d_in[30];
  P.q_w=(const float*)d_in[10]; P.q_b=(const float*)d_in[11]; P.k_w=(const float*)d_in[12];
  P.v_w=(const float*)d_in[13]; P.gate_w=(const float*)d_in[17]; P.out_w=(const float*)d_in[18];
  P.t_a_w=(const float*)d_in[26]; P.t_b_w=(const float*)d_in[27]; P.t_out_w=(const float*)d_in[28];
  P.tok_w=(const float*)d_in[31];

  // prologue: pack (3471) + zb (1024)
  prologue_kernel<<<4495,256,0,stream>>>(P, wsb, atom_pair,
      pair_ln_w, pair_ln_b, pair_w);
  // snp[which] = (LN(atom_proj)*w_which+b_which) @ W3[which]^T + b3[which]  -> bf16
  gemm_f<4,64><<<dim3(6,32,6),256,0,stream>>>(atom_proj, 0, W3T, 49152ll,
      B3, 384ll, SNP, 786432ll, NATOM, 384, 128, 3,
      aln_s_w, aln_s_b, t_aln_s_w, t_aln_s_b);
  // qkvg0 = modln_0(atom_single) @ [q|k|v|gate] + [q_b|0|0|0]  -> bf16
  gemm_f<1,64><<<dim3(8,64,1),256,0,stream>>>(atom_single, 0, WQKVGT, 0,
      BQ, 0, QKVG, 0, MR, 512, 128, 3,
      SNP, nullptr, nullptr, nullptr);

  for (int i=0;i<NBI;i++){
    const ushortx* snpA = SNP + (long long)(2*i)*786432;
    const ushortx* snpT = SNP + (long long)(2*i+1)*786432;
    ushortx* qin  = (i&1) ? QKVG2 : QKVG;
    ushortx* qout = (i&1) ? QKVG  : QKVG2;
    const float* afsrc = (i==0) ? atom_single : Af;
    if (i < NBI-1){
      fused_iter<0><<<256,256,0,stream>>>(afsrc, Af, qin,
          ZB + (long long)i*2097152, mask,
          WOUTT + (long long)i*16384, WABT + (long long)i*65536, WTOUTT + (long long)i*32768,
          WQKVGT + (long long)(i+1)*65536, BQ + (long long)(i+1)*512,
          snpA, snpT, SNP + (long long)(2*(i+1))*786432,
          qout, nullptr);
    } else {
      fused_iter<1><<<256,256,0,stream>>>(afsrc, Af, qin,
          ZB + (long long)i*2097152, mask,
          WOUTT + (long long)i*16384, WABT + (long long)i*65536, WTOUTT + (long long)i*32768,
          WTOKT, nullptr,
          snpA, snpT, nullptr,
          qout, QTOK);
    }
  }
  tokagg_kernel<<<TT,128,0,stream>>>(tok_idx, QTOK, (float*)d_out);
}

// Round 5
// 557.042 us; speedup vs baseline: 1.0405x; 1.0405x over previous
//
#include <hip/hip_runtime.h>
#include <math.h>

#define NATOM 2048
#define CD 128
#define SD 2
#define TT 512
#define CTD 384
#define NBI 3
#define MR 4096  // SD*NATOM

typedef unsigned short ushortx;
typedef __attribute__((ext_vector_type(8))) short bf16x8;
typedef __attribute__((ext_vector_type(4))) float f32x4;
typedef __attribute__((ext_vector_type(4))) unsigned short us4;

__device__ __forceinline__ float sigm(float x){ return 1.0f/(1.0f+expf(-x)); }
__device__ __forceinline__ ushortx f2b(float f){
  union { float f; unsigned u; } v; v.f = f;
  unsigned r = v.u + 0x7fffu + ((v.u>>16)&1u);
  return (ushortx)(r>>16);
}
__device__ __forceinline__ float b2f(ushortx u){
  union { unsigned u; float f; } v; v.u = ((unsigned)u)<<16; return v.f;
}
union U8 { ushortx u[8]; float4 v; };

// ---- workspace layout (byte offsets, 256-aligned) ----
#define OFFB_W3T    0ll        // ushort 6*384*128   [n][k] [gate|shift|og]
#define OFFB_B3     589824ll   // f32 6*384
#define OFFB_WQKVGT 599040ll   // ushort 3*512*128
#define OFFB_BQ     992256ll   // f32 3*512
#define OFFB_WOUTT  998400ll   // ushort 3*128*128
#define OFFB_WABT   1096704ll  // ushort 3*512*128
#define OFFB_WTOUTT 1489920ll  // ushort 3*128*256
#define OFFB_WTOKT  1686528ll  // ushort 384*128
#define OFFB_CNTI   1784832ll  // f32 512 (inverse token counts)
#define OFFB_SNP    2833408ll  // ushort 6*2048*384 (bf16)
#define OFFB_A      12270592ll // f32 4096*128
#define OFFB_QKVG   14367744ll // ushort 4096*512 (bf16)
#define OFFB_ZB     18562048ll // ushort 3*8*2048*128 (bf16)
#define OFFB_QKVG2  37436416ll // ushort 4096*512 (bf16, ping-pong partner)

struct WPtrs {
  const float *aln_gate_w, *aln_gate_b, *aln_shift_w, *og_w, *og_b;
  const float *t_aln_gate_w, *t_aln_gate_b, *t_aln_shift_w, *t_og_w, *t_og_b;
  const float *q_w, *q_b, *k_w, *v_w, *gate_w, *out_w;
  const float *t_a_w, *t_b_w, *t_out_w, *tok_w;
};

// prologue: weight pack (0..3470) + zb (3471..4494) + zero d_out (4495..6030)
// + inverse token counts (6031)
__global__ __launch_bounds__(256) void prologue_kernel(WPtrs P, char* __restrict__ wsb,
  const float* __restrict__ atom_pair,
  const float* __restrict__ plw, const float* __restrict__ plb, const float* __restrict__ pw,
  const int* __restrict__ tok_idx, float* __restrict__ outbuf, int out_n)
{
  int b = blockIdx.x;
  if (b < 3471){
    long long idx = (long long)b*256 + threadIdx.x;
    const long long s0=294912, s1=2304, s2=196608, s3=1536, s4=49152, s5=196608, s6=98304;
    if (idx < s0) { // W3T[which][n][k]
      int which = (int)(idx/49152); int r = (int)(idx%49152); int n=r/128, k=r%128;
      int i = which>>1, t = which&1;
      const float* src;
      if (n<128)      src = (t?P.t_aln_gate_w :P.aln_gate_w ) + i*16384 + k*128 + n;
      else if (n<256) src = (t?P.t_aln_shift_w:P.aln_shift_w) + i*16384 + k*128 + (n-128);
      else            src = (t?P.t_og_w       :P.og_w       ) + i*16384 + k*128 + (n-256);
      ((ushortx*)(wsb+OFFB_W3T))[idx] = f2b(*src); return;
    }
    idx -= s0;
    if (idx < s1) {
      int which = (int)(idx/384); int col = (int)(idx%384); int i=which>>1, t=which&1;
      float v = 0.f;
      if (col<128)       v = (t?P.t_aln_gate_b:P.aln_gate_b)[i*128+col];
      else if (col>=256) v = (t?P.t_og_b      :P.og_b      )[i*128+col-256];
      ((float*)(wsb+OFFB_B3))[idx] = v; return;
    }
    idx -= s1;
    if (idx < s2) { // WQKVGT[i][n][k]
      int i = (int)(idx/65536); int r = (int)(idx%65536); int n=r/128, k=r%128;
      int seg = n>>7, c = n&127;
      const float* src = (seg==0?P.q_w: seg==1?P.k_w: seg==2?P.v_w: P.gate_w) + i*16384 + k*128 + c;
      ((ushortx*)(wsb+OFFB_WQKVGT))[idx] = f2b(*src); return;
    }
    idx -= s2;
    if (idx < s3) {
      int i = (int)(idx/512); int col = (int)(idx%512);
      ((float*)(wsb+OFFB_BQ))[idx] = (col<128) ? P.q_b[i*128+col] : 0.f; return;
    }
    idx -= s3;
    if (idx < s4) { // WOUTT
      int i = (int)(idx/16384); int r = (int)(idx%16384); int n=r/128, k=r%128;
      ((ushortx*)(wsb+OFFB_WOUTT))[idx] = f2b(P.out_w[i*16384 + k*128 + n]); return;
    }
    idx -= s4;
    if (idx < s5) { // WABT
      int i = (int)(idx/65536); int r = (int)(idx%65536); int n=r/128, k=r%128;
      const float* src = (n<256) ? P.t_a_w + i*32768 + k*256 + n
                                 : P.t_b_w + i*32768 + k*256 + (n-256);
      ((ushortx*)(wsb+OFFB_WABT))[idx] = f2b(*src); return;
    }
    idx -= s5;
    if (idx < s6) { // WTOUTT
      int i = (int)(idx/32768); int r = (int)(idx%32768); int n=r/256, k=r%256;
      ((ushortx*)(wsb+OFFB_WTOUTT))[idx] = f2b(P.t_out_w[i*32768 + k*128 + n]); return;
    }
    idx -= s6;
    { // WTOKT
      int n = (int)(idx/128); int k = (int)(idx%128);
      ((ushortx*)(wsb+OFFB_WTOKT))[idx] = f2b(P.tok_w[k*384 + n]); return;
    }
  }
  if (b < 4495){
    // zb: zb_all[it][h][q][j] bf16, j in [0,128): key m = (q&~31)-48+j
    int idx = (b-3471)*256 + threadIdx.x;
    int q = idx>>7, j = idx&127;
    int m = (q & ~31) - 48 + j;
    bool ok = (m>=0 && m<NATOM);
    float x[16]; float mu=0.f, rs=0.f;
    if (ok){
      float s=0.f, sq=0.f;
      const float* p = atom_pair + ((long long)q*NATOM + m)*16;
      #pragma unroll
      for (int c=0;c<16;c++){ x[c]=p[c]; s+=x[c]; sq+=x[c]*x[c]; }
      mu = s*(1.f/16.f); float var = sq*(1.f/16.f)-mu*mu; rs = rsqrtf(var+1e-5f);
    }
    ushortx* zb = (ushortx*)(wsb+OFFB_ZB);
    #pragma unroll
    for (int it=0; it<NBI; it++){
      float out[8] = {0,0,0,0,0,0,0,0};
      if (ok){
        #pragma unroll
        for (int c=0;c<16;c++){
          float xn = (x[c]-mu)*rs*plw[it*16+c] + plb[it*16+c];
          #pragma unroll
          for (int h=0;h<8;h++) out[h] += xn * pw[it*128 + c*8 + h];
        }
      }
      #pragma unroll
      for (int h=0;h<8;h++)
        zb[(((long long)it*8+h)*NATOM + q)*128 + j] = f2b(out[h]);
    }
    return;
  }
  if (b < 6031){
    int i = (b-4495)*256 + threadIdx.x;
    if (i < out_n) outbuf[i] = 0.f;
    return;
  }
  { // inverse counts
    float* CNTI = (float*)(wsb+OFFB_CNTI);
    for (int t=threadIdx.x; t<TT; t+=256){
      int lo=0, hi=NATOM;
      while (lo<hi){ int mid=(lo+hi)>>1; if (tok_idx[mid] < t) lo=mid+1; else hi=mid; }
      int st = lo; lo = st; hi = NATOM;
      while (lo<hi){ int mid=(lo+hi)>>1; if (tok_idx[mid] <= t) lo=mid+1; else hi=mid; }
      int cnt = lo - st;
      CNTI[t] = 1.0f/(float)(cnt>0?cnt:1);
    }
  }
}

// Fused iteration: wide banded attention (all heads parallel, 5 barriers) +
// post-attention GEMM chain (round-2 proven body), 16 rows/block, 256 blocks.
template<int LAST>
__global__ __launch_bounds__(256) void fused_iter(
  const float* __restrict__ Afsrc, float* __restrict__ Af,
  const ushortx* __restrict__ QKVGin, const ushortx* __restrict__ zbg,
  const float* __restrict__ mask,
  const ushortx* __restrict__ Wout,    // [128][128]
  const ushortx* __restrict__ Wab,     // [512][128]
  const ushortx* __restrict__ Wtout,   // [128][256]
  const ushortx* __restrict__ WN,      // qkvg_next [512][128] | tok [384][128]
  const float*   __restrict__ biasN,   // [512] (null if LAST)
  const ushortx* __restrict__ snpA,    // [2048][384]
  const ushortx* __restrict__ snpT,
  const ushortx* __restrict__ snpN,    // null if LAST
  ushortx* __restrict__ QKVGout,
  const int* __restrict__ tokidx, const float* __restrict__ CNTI,
  float* __restrict__ OUT)
{
  __shared__ __align__(16) ushortx KST[128][128];  // K, chunk-swizzled: chunk^=(j>>3)
  __shared__ __align__(16) ushortx VST[128][128];  // V, linear
  __shared__ __align__(16) ushortx QST[16][128];
  __shared__ __align__(16) char R1Raw[34816];      // attn: zb[2][16][4][128] / gemm: Bt[2][64][136]
  __shared__ __align__(16) char PRaw[33792];       // attn: P f32[16][4][132] / gemm: A2t+Ht
  __shared__ __align__(16) float Afr[16][132];
  __shared__ __align__(16) ushortx XX[16*264];     // A1t (p<2) then Hs (p>=6)
  __shared__ float maskb[128];
  __shared__ float invL[16][8];
  __shared__ int   tokL[16];
  __shared__ float invT[16];

  ushortx (*Bt)[64][136]     = (ushortx(*)[64][136])R1Raw;
  ushortx (*ZR)[16][4][128]  = (ushortx(*)[16][4][128])R1Raw;
  float   (*Pm)[4][132]      = (float(*)[4][132])PRaw;
  ushortx (*A2t)[136]        = (ushortx(*)[136])PRaw;
  ushortx (*Ht)[264]         = (ushortx(*)[264])(PRaw + 4608);
  ushortx (*A1t)[136]        = (ushortx(*)[136])XX;
  ushortx (*Hs)[264]         = (ushortx(*)[264])XX;

  int tid = threadIdx.x, rowBase = blockIdx.x*16;
  int sIdx = rowBase>>11, n0 = rowBase&2047;
  int wbase = (n0 & ~31) - 48;
  int wave=tid>>6, lane=tid&63, lr=lane&15, lk=(lane>>4)*8;
  int wc = wave*16;
  int r = tid>>4, tcol = tid&15, c8 = tcol*8;
  long long grow = rowBase + r;
  int sr=tid>>2, csB=(tid&3)*32;
  int crow = (lane>>4)*4;

  // ---- staging ----
  { const float4* ap=(const float4*)&Afsrc[grow*128+c8];
    *(float4*)&Afr[r][c8]=ap[0]; *(float4*)&Afr[r][c8+4]=ap[1]; }
  if (tid < 128){
    int m = wbase + tid;
    maskb[tid] = (m>=0 && m<NATOM) ? (mask[m]-1.0f)*1e8f : -1e30f;
  }
  if (LAST && tid < 16){
    int t = tokidx[n0+tid]; tokL[tid]=t; invT[tid]=CNTI[t];
  }
  *(float4*)&QST[r][c8] = *(const float4*)&QKVGin[grow*512 + c8];
  #pragma unroll
  for (int it=0; it<16; ++it){
    int idx = tid + it*256;
    int j = idx>>5, c = idx&31;
    int m = wbase + j; int mc = m<0?0:(m>NATOM-1?NATOM-1:m);
    long long rowb = ((long long)(sIdx*NATOM+mc))*512;
    if (c < 16){
      float4 v = *(const float4*)&QKVGin[rowb + 128 + c*8];
      *(float4*)&KST[j][((c ^ (j>>3)) & 15)*8] = v;
    } else {
      int cv = c-16;
      float4 v = *(const float4*)&QKVGin[rowb + 256 + cv*8];
      *(float4*)&VST[j][cv*8] = v;
    }
  }
  #pragma unroll
  for (int it=0; it<8; ++it){
    int idx = tid + it*256;
    int hr = idx>>4, c = idx&15;
    int h = hr>>4, rr = hr&15;
    float4 v = *(const float4*)&zbg[((long long)h*NATOM + n0 + rr)*128 + c*8];
    *(float4*)&ZR[h>>2][rr][h&3][c*8] = v;
  }
  __syncthreads();   // B1: all staged

  // ---- attention: 2 half-phases of 4 heads ----
  #pragma unroll
  for (int half=0; half<2; ++half){
    // QK + softmax: thread (r,tcol) handles keys j = tcol*8..+7 for 4 heads
    #pragma unroll
    for (int hl=0; hl<4; ++hl){
      int h = half*4 + hl;
      float qv[16];
      { U8 qa, qb_;
        qa.v = *(const float4*)&QST[r][h*16];
        qb_.v = *(const float4*)&QST[r][h*16+8];
        #pragma unroll
        for (int t=0;t<8;t++){ qv[t]=b2f(qa.u[t]); qv[8+t]=b2f(qb_.u[t]); } }
      U8 za; za.v = *(const float4*)&ZR[half][r][hl][c8];
      int cs0 = (2*h) ^ tcol;
      int cs1 = (2*h+1) ^ tcol;
      float lv[8], pmax=-1e30f;
      #pragma unroll
      for (int u=0;u<8;u++){
        int j = c8 + u;
        U8 ka, kb_;
        ka.v = *(const float4*)&KST[j][cs0*8];
        kb_.v = *(const float4*)&KST[j][cs1*8];
        float dot = 0.f;
        #pragma unroll
        for (int t=0;t<8;t++) dot += qv[t]*b2f(ka.u[t]);
        #pragma unroll
        for (int t=0;t<8;t++) dot += qv[8+t]*b2f(kb_.u[t]);
        float L = dot*0.25f + b2f(za.u[u]) + maskb[j];
        lv[u]=L; pmax=fmaxf(pmax,L);
      }
      #pragma unroll
      for (int off=1; off<16; off<<=1) pmax = fmaxf(pmax, __shfl_xor(pmax,off));
      float4 e0, e1;
      e0.x=expf(lv[0]-pmax); e0.y=expf(lv[1]-pmax); e0.z=expf(lv[2]-pmax); e0.w=expf(lv[3]-pmax);
      e1.x=expf(lv[4]-pmax); e1.y=expf(lv[5]-pmax); e1.z=expf(lv[6]-pmax); e1.w=expf(lv[7]-pmax);
      float ps = e0.x+e0.y+e0.z+e0.w+e1.x+e1.y+e1.z+e1.w;
      *(float4*)&Pm[r][hl][c8]   = e0;
      *(float4*)&Pm[r][hl][c8+4] = e1;
      #pragma unroll
      for (int off=1; off<16; off<<=1) ps += __shfl_xor(ps,off);
      if (tcol == hl) invL[r][h] = 1.0f/ps;
    }
    __syncthreads();   // B2/B4: P + inv ready
    // PV: thread (r,tcol) owns 4 dims of this half
    {
      int hh = tcol>>2, d0 = half*64 + tcol*4;
      float a0=0.f,a1=0.f,a2=0.f,a3=0.f;
      const float* prow = &Pm[r][hh][0];
      #pragma unroll 8
      for (int j4=0; j4<128; j4+=4){
        float4 pj = *(const float4*)&prow[j4];
        us4 v0 = *(const us4*)&VST[j4  ][d0];
        us4 v1 = *(const us4*)&VST[j4+1][d0];
        us4 v2 = *(const us4*)&VST[j4+2][d0];
        us4 v3 = *(const us4*)&VST[j4+3][d0];
        a0 += pj.x*b2f(v0[0]); a1 += pj.x*b2f(v0[1]); a2 += pj.x*b2f(v0[2]); a3 += pj.x*b2f(v0[3]);
        a0 += pj.y*b2f(v1[0]); a1 += pj.y*b2f(v1[1]); a2 += pj.y*b2f(v1[2]); a3 += pj.y*b2f(v1[3]);
        a0 += pj.z*b2f(v2[0]); a1 += pj.z*b2f(v2[1]); a2 += pj.z*b2f(v2[2]); a3 += pj.z*b2f(v2[3]);
        a0 += pj.w*b2f(v3[0]); a1 += pj.w*b2f(v3[1]); a2 += pj.w*b2f(v3[2]); a3 += pj.w*b2f(v3[3]);
      }
      float inv = invL[r][half*4+hh];
      us4 gt = *(const us4*)&QKVGin[grow*512 + 384 + d0];
      us4 st;
      st[0]=f2b(sigm(b2f(gt[0]))*a0*inv);
      st[1]=f2b(sigm(b2f(gt[1]))*a1*inv);
      st[2]=f2b(sigm(b2f(gt[2]))*a2*inv);
      st[3]=f2b(sigm(b2f(gt[3]))*a3*inv);
      *(us4*)&A1t[r][d0] = st;
    }
    if (half==0) __syncthreads();   // B3: P free for QK half1
  }
  // stage Bt[0] (Wout cols 0..63) — R1 free now (zb consumed at B4)
  {
    const float4* bg = (const float4*)(Wout + (long long)sr*128 + csB);
    #pragma unroll
    for (int u=0;u<4;u++) *(float4*)&Bt[0][sr][csB+u*8] = bg[u];
  }

  // ---- GEMM pass loop (round-2 proven body) ----
  const int NP = LAST ? 20 : 22;
  f32x4 acc = (f32x4){0.f,0.f,0.f,0.f};
  for (int p=0; p<NP; p++){
    __syncthreads();
    if (p+1 < NP){
      int pn = p+1;
      const ushortx* bsrc; long long bstride;
      if (pn<2)      { bsrc = Wout  + (long long)(pn*64)*128;                      bstride=128; }
      else if (pn<10){ bsrc = Wab   + (long long)((pn-2)*64)*128;                  bstride=128; }
      else if (pn<14){ int q=pn-10; bsrc = Wtout + (long long)((q>>1)*64)*256 + (q&1)*128; bstride=256; }
      else           { int q=pn-14; bsrc = WN    + (long long)(q*64)*128;          bstride=128; }
      const float4* bg=(const float4*)(bsrc + (long long)sr*bstride + csB);
      #pragma unroll
      for (int u=0;u<4;u++) *(float4*)&Bt[pn&1][sr][csB+u*8] = bg[u];
    }
    if (p==2){
      float x[8], s=0.f, sq=0.f;
      #pragma unroll
      for (int u=0;u<8;u++){ x[u]=Afr[r][c8+u]; s+=x[u]; sq+=x[u]*x[u]; }
      #pragma unroll
      for (int off=1; off<16; off<<=1){ s+=__shfl_xor(s,off); sq+=__shfl_xor(sq,off); }
      float mu=s*(1.f/128.f), rs=rsqrtf(sq*(1.f/128.f)-mu*mu+1e-5f);
      const ushortx* sp = snpT + (long long)((int)grow&2047)*384;
      U8 ga,ha,pk; ga.v=*(const float4*)&sp[c8]; ha.v=*(const float4*)&sp[128+c8];
      #pragma unroll
      for (int t=0;t<8;t++) pk.u[t]=f2b(sigm(b2f(ga.u[t]))*((x[t]-mu)*rs)+b2f(ha.u[t]));
      *(float4*)&A2t[r][c8]=pk.v;
      __syncthreads();
    }
    if (p==14){
      float x[8], s=0.f, sq=0.f;
      #pragma unroll
      for (int u=0;u<8;u++){ x[u]=Afr[r][c8+u]; s+=x[u]; sq+=x[u]*x[u]; }
      { float4* ap=(float4*)&Af[grow*128+c8];
        ap[0]=*(float4*)&Afr[r][c8]; ap[1]=*(float4*)&Afr[r][c8+4]; }
      if (LAST){
        U8 pk;
        #pragma unroll
        for (int t=0;t<8;t++) pk.u[t]=f2b(x[t]);
        *(float4*)&A2t[r][c8]=pk.v;
      } else {
        #pragma unroll
        for (int off=1; off<16; off<<=1){ s+=__shfl_xor(s,off); sq+=__shfl_xor(sq,off); }
        float mu=s*(1.f/128.f), rs=rsqrtf(sq*(1.f/128.f)-mu*mu+1e-5f);
        const ushortx* sp = snpN + (long long)((int)grow&2047)*384;
        U8 ga,ha,pk; ga.v=*(const float4*)&sp[c8]; ha.v=*(const float4*)&sp[128+c8];
        #pragma unroll
        for (int t=0;t<8;t++) pk.u[t]=f2b(sigm(b2f(ga.u[t]))*((x[t]-mu)*rs)+b2f(ha.u[t]));
        *(float4*)&A2t[r][c8]=pk.v;
      }
      __syncthreads();
    }
    if (p!=11 && p!=13) acc=(f32x4){0.f,0.f,0.f,0.f};
    #pragma unroll
    for (int ks=0; ks<4; ks++){
      bf16x8 a;
      if (p<2)       a = *(const bf16x8*)&A1t[lr][ks*32+lk];
      else if (p<10) a = *(const bf16x8*)&A2t[lr][ks*32+lk];
      else if (p<14){ int kc=(p-10)&1; a = *(const bf16x8*)&Hs[lr][kc*128+ks*32+lk]; }
      else           a = *(const bf16x8*)&A2t[lr][ks*32+lk];
      bf16x8 b = *(const bf16x8*)&Bt[p&1][wc+lr][ks*32+lk];
      acc = __builtin_amdgcn_mfma_f32_16x16x32_bf16(a,b,acc,0,0,0);
    }
    if (p<2){
      int ccol = p*64 + wc + lr;
      #pragma unroll
      for (int rr=0;rr<4;rr++){
        int rrow=crow+rr;
        float g=b2f(snpA[(long long)((rowBase+rrow)&2047)*384 + 256 + ccol]);
        Afr[rrow][ccol]+=sigm(g)*acc[rr];
      }
    } else if (p<10){
      int cp=p-2; int ccol=cp*64+wc+lr;
      if (cp<4){
        #pragma unroll
        for (int rr=0;rr<4;rr++) Ht[crow+rr][ccol]=f2b(acc[rr]);
      } else {
        int hc=ccol-256;
        #pragma unroll
        for (int rr=0;rr<4;rr++){
          float ha=b2f(Ht[crow+rr][hc]);
          Hs[crow+rr][hc]=f2b(ha*sigm(ha)*acc[rr]);
        }
      }
    } else if (p==11 || p==13){
      int cp=(p-10)>>1; int ccol=cp*64+wc+lr;
      #pragma unroll
      for (int rr=0;rr<4;rr++){
        int rrow=crow+rr;
        float g=b2f(snpT[(long long)((rowBase+rrow)&2047)*384 + 256 + ccol]);
        Afr[rrow][ccol]+=sigm(g)*acc[rr];
      }
    } else if (p>=14){
      int q=p-14; int ccol=q*64+wc+lr;
      if (LAST){
        #pragma unroll
        for (int rr=0;rr<4;rr++){
          int rloc = crow+rr;
          int rowg = rowBase + rloc;
          int s = rowg>>11;
          float v = fmaxf(acc[rr],0.f) * invT[rloc];
          atomicAdd(&OUT[((long long)(s*TT + tokL[rloc])*CTD) + ccol], v);
        }
      } else {
        float bv=biasN[ccol];
        #pragma unroll
        for (int rr=0;rr<4;rr++)
          QKVGout[(long long)(rowBase+crow+rr)*512 + ccol]=f2b(acc[rr]+bv);
      }
    }
  }
}

// MFMA GEMM with fused LN A-staging (SNP production and qkvg0). AM=1 or 4.
template<int AM, int BM>
__global__ __launch_bounds__(256) void gemm_f(
    const void* __restrict__ Asrc, long long strideA,
    const ushortx* __restrict__ B, long long strideB,
    const float* __restrict__ bias, long long strideBias,
    void* Cv, long long strideC,
    int M, int N, int K, int mode,
    const void* __restrict__ p1, const void* __restrict__ p2,
    const void* __restrict__ p3, const void* __restrict__ p4)
{
  constexpr int CG  = 256/BM;
  constexpr int XC  = 128/CG;
  constexpr int F4  = XC/8;
  constexpr int ACI = BM/32;
  int z = blockIdx.z;
  B += z*strideB;
  if (bias) bias += z*strideBias;
  ushortx* Cu = (ushortx*)Cv + z*strideC;
  __shared__ __align__(16) ushortx At[BM][136];
  __shared__ __align__(16) ushortx Bt[64][136];
  int tid = threadIdx.x;
  int rowBase = blockIdx.y*BM, colBase = blockIdx.x*64;
  int wave = tid>>6, lane = tid&63;
  int wr = (wave>>1)*(BM/2), wc = (wave&1)*32;
  int lr = lane&15, lk = (lane>>4)*8;
  f32x4 acc[ACI][2];
  #pragma unroll
  for (int i=0;i<ACI;i++)
    #pragma unroll
    for (int j=0;j<2;j++) acc[i][j] = (f32x4){0.f,0.f,0.f,0.f};

  int sr = tid/CG, q = tid%CG, cs = q*XC;
  int row = rowBase + sr;
  int bsr = tid>>2, bq = tid&3, bcs = bq*32;

  for (int kc=0; kc<K; kc+=128){
    if (kc) __syncthreads();
    { // LN staging, K=128
      const float* arow = (const float*)Asrc + (long long)row*128;
      float x[XC]; float s=0.f, sq=0.f;
      const float4* ar = (const float4*)(arow + cs);
      #pragma unroll
      for (int u=0;u<XC/4;u++){
        float4 t = ar[u];
        x[4*u]=t.x; x[4*u+1]=t.y; x[4*u+2]=t.z; x[4*u+3]=t.w;
        s += t.x+t.y+t.z+t.w;
        sq += t.x*t.x+t.y*t.y+t.z*t.z+t.w*t.w;
      }
      #pragma unroll
      for (int off=1; off<CG; off<<=1){ s += __shfl_xor(s,off); sq += __shfl_xor(sq,off); }
      float mu = s*(1.f/128.f), var = sq*(1.f/128.f)-mu*mu;
      float rs = rsqrtf(var + 1e-5f);
      if (AM==1){
        const ushortx* sp = (const ushortx*)p1 + (long long)(row & (NATOM-1))*384;
        const float4* gr = (const float4*)(sp + cs);
        const float4* hr = (const float4*)(sp + 128 + cs);
        #pragma unroll
        for (int u=0;u<F4;u++){
          U8 ga, ha, pk;
          ga.v = gr[u]; ha.v = hr[u];
          #pragma unroll
          for (int t=0;t<8;t++)
            pk.u[t] = f2b(sigm(b2f(ga.u[t]))*((x[8*u+t]-mu)*rs) + b2f(ha.u[t]));
          *(float4*)&At[sr][cs+u*8] = pk.v;
        }
      } else { // AM==4
        int iw = z>>1, tw = z&1;
        const float* w = (const float*)(tw?p3:p1) + iw*128;
        const float* b = (const float*)(tw?p4:p2) + iw*128;
        const float4* wrp = (const float4*)(w + cs);
        const float4* brp = (const float4*)(b + cs);
        #pragma unroll
        for (int u=0;u<F4;u++){
          float4 wa = wrp[2*u], wb = wrp[2*u+1];
          float4 ba = brp[2*u], bb = brp[2*u+1];
          U8 pk;
          pk.u[0]=f2b((x[8*u  ]-mu)*rs*wa.x+ba.x);
          pk.u[1]=f2b((x[8*u+1]-mu)*rs*wa.y+ba.y);
          pk.u[2]=f2b((x[8*u+2]-mu)*rs*wa.z+ba.z);
          pk.u[3]=f2b((x[8*u+3]-mu)*rs*wa.w+ba.w);
          pk.u[4]=f2b((x[8*u+4]-mu)*rs*wb.x+bb.x);
          pk.u[5]=f2b((x[8*u+5]-mu)*rs*wb.y+bb.y);
          pk.u[6]=f2b((x[8*u+6]-mu)*rs*wb.z+bb.z);
          pk.u[7]=f2b((x[8*u+7]-mu)*rs*wb.w+bb.w);
          *(float4*)&At[sr][cs+u*8] = pk.v;
        }
      }
    }
    {
      const float4* bg = (const float4*)(B + (long long)(colBase+bsr)*K + kc + bcs);
      #pragma unroll
      for (int u=0;u<4;u++) *(float4*)&Bt[bsr][bcs+u*8] = bg[u];
    }
    __syncthreads();
    #pragma unroll
    for (int ks=0; ks<4; ks++){
      bf16x8 b0 = *(const bf16x8*)&Bt[wc+lr][ks*32+lk];
      bf16x8 b1 = *(const bf16x8*)&Bt[wc+16+lr][ks*32+lk];
      #pragma unroll
      for (int i=0;i<ACI;i++){
        bf16x8 a = *(const bf16x8*)&At[wr+i*16+lr][ks*32+lk];
        acc[i][0] = __builtin_amdgcn_mfma_f32_16x16x32_bf16(a,b0,acc[i][0],0,0,0);
        acc[i][1] = __builtin_amdgcn_mfma_f32_16x16x32_bf16(a,b1,acc[i][1],0,0,0);
      }
    }
  }
  int crow0 = rowBase + wr + (lane>>4)*4;
  int ccol0 = colBase + wc + lr;
  #pragma unroll
  for (int i=0;i<ACI;i++){
    #pragma unroll
    for (int j=0;j<2;j++){
      int col = ccol0 + j*16;
      float bv = bias ? bias[col] : 0.f;
      #pragma unroll
      for (int rr=0; rr<4; rr++){
        int rrow = crow0 + i*16 + rr;
        float v = acc[i][j][rr] + bv;
        long long ci = (long long)rrow*N + col;
        Cu[ci] = f2b(v);
        (void)mode;
      }
    }
  }
}

extern "C" void kernel_launch(void* const* d_in, const int* in_sizes, int n_in,
                              void* d_out, int out_size, void* d_ws, size_t ws_size,
                              hipStream_t stream)
{
  const float* atom_single = (const float*)d_in[0];
  const float* atom_proj   = (const float*)d_in[1];
  const float* atom_pair   = (const float*)d_in[2];
  const float* mask        = (const float*)d_in[3];
  const int*   tok_idx     = (const int*)  d_in[4];
  const float* aln_s_w     = (const float*)d_in[5];
  const float* aln_s_b     = (const float*)d_in[6];
  const float* pair_ln_w   = (const float*)d_in[14];
  const float* pair_ln_b   = (const float*)d_in[15];
  const float* pair_w      = (const float*)d_in[16];
  const float* t_aln_s_w   = (const float*)d_in[21];
  const float* t_aln_s_b   = (const float*)d_in[22];

  char* wsb = (char*)d_ws;
  ushortx* W3T    = (ushortx*)(wsb+OFFB_W3T);
  float*   B3     = (float*)  (wsb+OFFB_B3);
  ushortx* WQKVGT = (ushortx*)(wsb+OFFB_WQKVGT);
  float*   BQ     = (float*)  (wsb+OFFB_BQ);
  ushortx* WOUTT  = (ushortx*)(wsb+OFFB_WOUTT);
  ushortx* WABT   = (ushortx*)(wsb+OFFB_WABT);
  ushortx* WTOUTT = (ushortx*)(wsb+OFFB_WTOUTT);
  ushortx* WTOKT  = (ushortx*)(wsb+OFFB_WTOKT);
  float*   CNTI   = (float*)  (wsb+OFFB_CNTI);
  ushortx* SNP    = (ushortx*)(wsb+OFFB_SNP);
  float*   Af     = (float*)  (wsb+OFFB_A);
  ushortx* QKVG   = (ushortx*)(wsb+OFFB_QKVG);
  ushortx* QKVG2  = (ushortx*)(wsb+OFFB_QKVG2);
  ushortx* ZB     = (ushortx*)(wsb+OFFB_ZB);

  WPtrs P;
  P.aln_gate_w=(const float*)d_in[7];  P.aln_gate_b=(const float*)d_in[8];  P.aln_shift_w=(const float*)d_in[9];
  P.og_w=(const float*)d_in[19]; P.og_b=(const float*)d_in[20];
  P.t_aln_gate_w=(const float*)d_in[23]; P.t_aln_gate_b=(const float*)d_in[24]; P.t_aln_shift_w=(const float*)d_in[25];
  P.t_og_w=(const float*)d_in[29]; P.t_og_b=(const float*)d_in[30];
  P.q_w=(const float*)d_in[10]; P.q_b=(const float*)d_in[11]; P.k_w=(const float*)d_in[12];
  P.v_w=(const float*)d_in[13]; P.gate_w=(const float*)d_in[17]; P.out_w=(const float*)d_in[18];
  P.t_a_w=(const float*)d_in[26]; P.t_b_w=(const float*)d_in[27]; P.t_out_w=(const float*)d_in[28];
  P.tok_w=(const float*)d_in[31];

  // prologue: pack (3471) + zb (1024) + zero-out (1536) + counts (1)
  prologue_kernel<<<6032,256,0,stream>>>(P, wsb, atom_pair,
      pair_ln_w, pair_ln_b, pair_w, tok_idx, (float*)d_out, SD*TT*CTD);
  // snp[which] = (LN(atom_proj)*w_which+b_which) @ W3[which]^T + b3[which]  -> bf16
  gemm_f<4,64><<<dim3(6,32,6),256,0,stream>>>(atom_proj, 0, W3T, 49152ll,
      B3, 384ll, SNP, 786432ll, NATOM, 384, 128, 3,
      aln_s_w, aln_s_b, t_aln_s_w, t_aln_s_b);
  // qkvg0 = modln_0(atom_single) @ [q|k|v|gate] + [q_b|0|0|0]  -> bf16
  gemm_f<1,64><<<dim3(8,64,1),256,0,stream>>>(atom_single, 0, WQKVGT, 0,
      BQ, 0, QKVG, 0, MR, 512, 128, 3,
      SNP, nullptr, nullptr, nullptr);

  for (int i=0;i<NBI;i++){
    const ushortx* snpA = SNP + (long long)(2*i)*786432;
    const ushortx* snpT = SNP + (long long)(2*i+1)*786432;
    ushortx* qin  = (i&1) ? QKVG2 : QKVG;
    ushortx* qout = (i&1) ? QKVG  : QKVG2;
    const float* afsrc = (i==0) ? atom_single : Af;
    if (i < NBI-1){
      fused_iter<0><<<256,256,0,stream>>>(afsrc, Af, qin,
          ZB + (long long)i*2097152, mask,
          WOUTT + (long long)i*16384, WABT + (long long)i*65536, WTOUTT + (long long)i*32768,
          WQKVGT + (long long)(i+1)*65536, BQ + (long long)(i+1)*512,
          snpA, snpT, SNP + (long long)(2*(i+1))*786432,
          qout, nullptr, nullptr, nullptr);
    } else {
      fused_iter<1><<<256,256,0,stream>>>(afsrc, Af, qin,
          ZB + (long long)i*2097152, mask,
          WOUTT + (long long)i*16384, WABT + (long long)i*65536, WTOUTT + (long long)i*32768,
          WTOKT, nullptr,
          snpA, snpT, nullptr,
          qout, tok_idx, CNTI, (float*)d_out);
    }
  }
}